// Round 3
// baseline (576.654 us; speedup 1.0000x reference)
//
#include <hip/hip_runtime.h>
#include <hip/hip_bf16.h>

#define S_LEN 2048
#define HID 4096
#define NH 32
#define NKV 8
#define DH 128
#define QKV_N ((NH + 2 * NKV) * DH) /* 6144 */
#define SCALE_ATT 0.08838834764831845f /* 128^-0.5 */
#define SCALE2_ATT 0.12751744f         /* SCALE_ATT * log2(e) */

typedef __bf16 bf16;
typedef __bf16 bf16x8 __attribute__((ext_vector_type(8)));
typedef __bf16 bf16x4 __attribute__((ext_vector_type(4)));
typedef float f32x4 __attribute__((ext_vector_type(4)));
typedef float f32x16 __attribute__((ext_vector_type(16)));

__device__ inline f32x4 mfma16(bf16x8 a, bf16x8 b, f32x4 c) {
    return __builtin_amdgcn_mfma_f32_16x16x32_bf16(a, b, c, 0, 0, 0);
}
__device__ inline f32x16 mfma32(bf16x8 a, bf16x8 b, f32x16 c) {
    return __builtin_amdgcn_mfma_f32_32x32x16_bf16(a, b, c, 0, 0, 0);
}

__device__ inline bf16x8 load8(const float* p) {
    const float4 a = ((const float4*)p)[0];
    const float4 b = ((const float4*)p)[1];
    bf16x8 r;
    r[0] = (bf16)a.x; r[1] = (bf16)a.y; r[2] = (bf16)a.z; r[3] = (bf16)a.w;
    r[4] = (bf16)b.x; r[5] = (bf16)b.y; r[6] = (bf16)b.z; r[7] = (bf16)b.w;
    return r;
}
__device__ inline bf16x8 load8(const bf16* p) { return *(const bf16x8*)p; }

// direct global->LDS DMA, 16 bytes/lane. LDS dest is wave-uniform base + lane*16.
__device__ inline void load_lds16(const bf16* g, bf16* lds_base) {
    __builtin_amdgcn_global_load_lds(
        (const __attribute__((address_space(1))) void*)g,
        (__attribute__((address_space(3))) void*)lds_base, 16, 0, 0);
}

// pack 2 f32 -> 1 u32 holding 2 bf16
__device__ inline unsigned pack2_bf16(float lo, float hi) {
    union { bf16 h[2]; unsigned u; } r;
    r.h[0] = (bf16)lo;
    r.h[1] = (bf16)hi;
    return r.u;
}

// fp32 -> bf16 bulk convert (8 elts/thread)
__global__ __launch_bounds__(256) void cvt_kernel(const float* __restrict__ src,
                                                  bf16* __restrict__ dst, int n8) {
    int i = blockIdx.x * 256 + threadIdx.x;
    if (i >= n8) return;
    *(bf16x8*)&dst[(size_t)i * 8] = load8(&src[(size_t)i * 8]);
}

// ---------------------------------------------------------------------------
// 256-row-tile GEMM with counted-vmcnt pipeline (T3/T4/T5 + T2 swizzle + T1).
// C[M x N] = A[M x K] @ B[N x K]^T, bf16 in. BM=256, BN=256 or 128, BK=64.
// 512 threads = 8 waves (2 M x 4 N), per-wave tile 128 x (BN/4), 32x32x16 MFMA.
// LDS double-buffered; per iter: issue next-tile global_load_lds into the
// other buffer, THEN s_waitcnt vmcnt(8|6) (counted - next tile's loads stay
// in flight across both barriers and all MFMA), raw s_barrier, compute.
// LDS layout: [rows][64] bf16, chunk c (16B) of row r at slot c^(r&7)
// (identical swizzle to the 0-conflict 128^2 kernel).
// MFMA layout (verified end-to-end by attn kernel): mfma32(a,b) -> per lane
// C[row = (r&3)+8*(r>>2)+4*(lane>>5) (+32*frag)][col = lane&31].
// ---------------------------------------------------------------------------
template <int BN, typename OutT>
__global__ __launch_bounds__(512, 2) void gemm_8ph(const bf16* __restrict__ A,
                                                   const bf16* __restrict__ B,
                                                   OutT* __restrict__ C,
                                                   int K, int lda, int ldc) {
    constexpr int WTN = BN / 4;     // per-wave N extent
    constexpr int NREP = WTN / 32;  // 32-wide frags per wave (2 or 1)
    constexpr int BLOADS = BN / 64; // B stage calls per wave (4 or 2)
    extern __shared__ char smem[];
    bf16* As = (bf16*)smem;                       // [2][256*64]
    bf16* Bs = (bf16*)(smem + 2 * 256 * 64 * 2);  // [2][BN*64]

    const int tid = threadIdx.x;
    const int lane = tid & 63;
    const int w = tid >> 6;     // 0..7
    const int wm = w >> 2;      // 0..1
    const int wn = w & 3;       // 0..3
    const int ln = lane & 31;
    const int hi = lane >> 5;
    const int rseg = lane >> 3; // row within 8-row staging group
    const int gc = (lane & 7) ^ rseg; // swizzled source chunk

    // XCD-bijective block swizzle (grids here have nwg % 8 == 0)
    const int nwg = (int)(gridDim.x * gridDim.y);
    const int wg = (int)(blockIdx.y * gridDim.x + blockIdx.x);
    const int swz = (wg & 7) * (nwg >> 3) + (wg >> 3);
    const int tm = swz / (int)gridDim.x;
    const int tn = swz - tm * (int)gridDim.x;
    const int m0 = tm * 256;
    const int n0 = tn * BN;

    const int NT = K >> 6;

    auto stage = [&](int b, int kt) {
        const int k0 = kt * 64;
        const bf16* Ag = &A[(size_t)(m0 + w * 32 + rseg) * lda + k0 + gc * 8];
        bf16* Al = &As[b * (256 * 64) + (w * 32) * 64];
#pragma unroll
        for (int j = 0; j < 4; ++j)
            load_lds16(Ag + (size_t)j * 8 * lda, Al + j * 512);
        const bf16* Bg = &B[(size_t)(n0 + w * (BN / 8) + rseg) * K + k0 + gc * 8];
        bf16* Bl = &Bs[b * (BN * 64) + (w * (BN / 8)) * 64];
#pragma unroll
        for (int j = 0; j < BLOADS; ++j)
            load_lds16(Bg + (size_t)j * 8 * K, Bl + j * 512);
    };

    f32x16 acc[4][NREP];
#pragma unroll
    for (int mi = 0; mi < 4; ++mi)
#pragma unroll
        for (int j = 0; j < NREP; ++j)
#pragma unroll
            for (int r = 0; r < 16; ++r) acc[mi][j][r] = 0.f;

    stage(0, 0);
    int buf = 0;
    for (int kt = 0; kt < NT; ++kt) {
        if (kt + 1 < NT) {
            stage(buf ^ 1, kt + 1); // next tile DMA: stays in flight across barriers
            if constexpr (BN == 256)
                asm volatile("s_waitcnt vmcnt(8)" ::: "memory"); // my current-tile loads landed
            else
                asm volatile("s_waitcnt vmcnt(6)" ::: "memory");
        } else {
            asm volatile("s_waitcnt vmcnt(0)" ::: "memory");
        }
        __builtin_amdgcn_s_barrier(); // everyone's current-tile DMA landed
        __builtin_amdgcn_sched_barrier(0);

        const bf16* Ab = &As[buf * (256 * 64)];
        const bf16* Bb = &Bs[buf * (BN * 64)];
        bf16x8 bfr[NREP][4];
#pragma unroll
        for (int j = 0; j < NREP; ++j)
#pragma unroll
            for (int kk = 0; kk < 4; ++kk) {
                const int n = wn * WTN + j * 32 + ln;
                bfr[j][kk] = *(const bf16x8*)&Bb[n * 64 + (((2 * kk + hi) ^ (ln & 7)) * 8)];
            }
#pragma unroll
        for (int p = 0; p < 2; ++p) {
            bf16x8 af[2][4];
#pragma unroll
            for (int i = 0; i < 2; ++i)
#pragma unroll
                for (int kk = 0; kk < 4; ++kk) {
                    const int m = wm * 128 + (p * 2 + i) * 32 + ln;
                    af[i][kk] = *(const bf16x8*)&Ab[m * 64 + (((2 * kk + hi) ^ (ln & 7)) * 8)];
                }
            __builtin_amdgcn_s_setprio(1);
#pragma unroll
            for (int i = 0; i < 2; ++i)
#pragma unroll
                for (int j = 0; j < NREP; ++j)
#pragma unroll
                    for (int kk = 0; kk < 4; ++kk)
                        acc[p * 2 + i][j] = mfma32(af[i][kk], bfr[j][kk], acc[p * 2 + i][j]);
            __builtin_amdgcn_s_setprio(0);
        }
        __builtin_amdgcn_sched_barrier(0);
        asm volatile("s_waitcnt lgkmcnt(0)" ::: "memory"); // my LDS reads complete
        __builtin_amdgcn_s_barrier(); // all reads of buf done -> next iter may overwrite
        __builtin_amdgcn_sched_barrier(0);
        buf ^= 1;
    }

    // epilogue: C[row][col], row from A-frag index, col = ln (attn-verified map)
#pragma unroll
    for (int mi = 0; mi < 4; ++mi)
#pragma unroll
        for (int j = 0; j < NREP; ++j)
#pragma unroll
            for (int r = 0; r < 16; ++r) {
                int row = m0 + wm * 128 + mi * 32 + (r & 3) + 8 * (r >> 2) + 4 * hi;
                int col = n0 + wn * WTN + j * 32 + ln;
                C[(size_t)row * ldc + col] = (OutT)acc[mi][j][r];
            }
}

// ---------------- fallback fp32-staging GEMM (low-workspace path) ----------------
template <typename AT, typename OutT>
__global__ __launch_bounds__(256) void gemm_bt(const AT* __restrict__ A,
                                               const float* __restrict__ B,
                                               OutT* __restrict__ C,
                                               int K, int lda, int ldc) {
    const int tid = threadIdx.x;
    const int lane = tid & 63;
    const int w = tid >> 6;
    const int m0 = blockIdx.y * 128;
    const int n0 = blockIdx.x * 128;
    const int wm = (w >> 1) * 64;
    const int wn = (w & 1) * 64;
    const int ln = lane & 15;
    const int qo = lane >> 4;

    __shared__ bf16 As[128 * 72];
    __shared__ bf16 Bs[128 * 72];

    f32x4 acc[4][4];
#pragma unroll
    for (int mi = 0; mi < 4; ++mi)
#pragma unroll
        for (int ni = 0; ni < 4; ++ni) acc[mi][ni] = f32x4{0.f, 0.f, 0.f, 0.f};

    for (int k0 = 0; k0 < K; k0 += 64) {
#pragma unroll
        for (int i = 0; i < 4; ++i) {
            int v = tid + i * 256;
            int row = v >> 3;
            int col = (v & 7) * 8;
            *(bf16x8*)&As[row * 72 + col] = load8(&A[(size_t)(m0 + row) * lda + k0 + col]);
            *(bf16x8*)&Bs[row * 72 + col] = load8(&B[(size_t)(n0 + row) * K + k0 + col]);
        }
        __syncthreads();
#pragma unroll
        for (int kk = 0; kk < 64; kk += 32) {
            bf16x8 af[4], bfr[4];
#pragma unroll
            for (int mi = 0; mi < 4; ++mi)
                af[mi] = *(const bf16x8*)&As[(wm + mi * 16 + ln) * 72 + kk + qo * 8];
#pragma unroll
            for (int ni = 0; ni < 4; ++ni)
                bfr[ni] = *(const bf16x8*)&Bs[(wn + ni * 16 + ln) * 72 + kk + qo * 8];
#pragma unroll
            for (int mi = 0; mi < 4; ++mi)
#pragma unroll
                for (int ni = 0; ni < 4; ++ni)
                    acc[mi][ni] = mfma16(af[mi], bfr[ni], acc[mi][ni]);
        }
        __syncthreads();
    }
#pragma unroll
    for (int mi = 0; mi < 4; ++mi)
#pragma unroll
        for (int ni = 0; ni < 4; ++ni)
#pragma unroll
            for (int r = 0; r < 4; ++r) {
                int row = m0 + wm + mi * 16 + qo * 4 + r;
                int col = n0 + wn + ni * 16 + ln;
                C[(size_t)row * ldc + col] = (OutT)acc[mi][ni][r];
            }
}

// RoPE in-place on bf16 qkv buffer
__global__ __launch_bounds__(256) void rope_kernel(bf16* __restrict__ qkv,
                                                   const int* __restrict__ positions) {
    int idx = blockIdx.x * 256 + threadIdx.x;
    const int total = S_LEN * (NH + NKV) * 64;
    if (idx >= total) return;
    int d = idx & 63;
    int t = idx >> 6;
    int head = t % (NH + NKV);
    int s = t / (NH + NKV);
    size_t base = (size_t)s * QKV_N + (head < NH ? head * DH : NH * DH + (head - NH) * DH);
    float x1 = (float)qkv[base + d];
    float x2 = (float)qkv[base + d + 64];
    float pos = (float)positions[s];
    float inv = expf(-0.21586735246819178f * (float)d);
    float ang = pos * inv;
    float c = cosf(ang);
    float sn = sinf(ang);
    qkv[base + d] = (bf16)(x1 * c - x2 * sn);
    qkv[base + d + 64] = (bf16)(x2 * c + x1 * sn);
}

// Pre-transpose V into vt_g[kvh][d][s]
__global__ __launch_bounds__(256) void vtrans_kernel(const bf16* __restrict__ qkv,
                                                     bf16* __restrict__ vt_g) {
    const int tid = threadIdx.x;
    const int s0 = blockIdx.x * 64;
    const int kvh = blockIdx.y;
    __shared__ bf16 Ls[64 * 136];
#pragma unroll
    for (int i = 0; i < 4; ++i) {
        int v = tid + i * 256;
        int row = v >> 4;
        int col = (v & 15) * 8;
        *(bf16x8*)&Ls[row * 136 + col] =
            *(const bf16x8*)&qkv[(size_t)(s0 + row) * QKV_N + (NH + NKV) * DH + kvh * DH + col];
    }
    __syncthreads();
#pragma unroll
    for (int i = 0; i < 4; ++i) {
        int u = tid + i * 256;
        int d = u >> 3;
        int sg = (u & 7) * 8;
        bf16x8 r;
#pragma unroll
        for (int j = 0; j < 8; ++j) r[j] = Ls[(sg + j) * 136 + d];
        *(bf16x8*)&vt_g[((size_t)kvh * DH + d) * S_LEN + s0 + sg] = r;
    }
}

// ---------------------------------------------------------------------------
// Flash attention (round-2 proven): 4 warps x 32 q-rows, KVBLK=64, 32x32x16
// MFMA, swapped QK^T, in-register softmax, shfl cross-half P exchange,
// O^T = Vt @ P^T, XOR-swizzled LDS via global_load_lds, 1 barrier/tile.
// ---------------------------------------------------------------------------
__global__ __launch_bounds__(256) void attn_kernel(bf16* __restrict__ qkv,
                                                   const bf16* __restrict__ vt_g) {
    const int tid = threadIdx.x;
    const int lane = tid & 63;
    const int w = tid >> 6;
    const int ln = lane & 31;
    const int hi = lane >> 5;
    const int hq = blockIdx.x;
    const int qtile = (int)gridDim.y - 1 - (int)blockIdx.y; // heavy first
    const int kvh = hq >> 2;
    const int q0 = qtile * 128;
    const int qrow = q0 + w * 32 + ln;

    __shared__ __align__(128) bf16 Ks[2][64 * 128];
    __shared__ __align__(128) bf16 Vt[2][128 * 64];

    bf16x8 qf[8];
    {
        const bf16* qptr = qkv + (size_t)qrow * QKV_N + hq * DH + hi * 8;
#pragma unroll
        for (int s = 0; s < 8; ++s) qf[s] = *(const bf16x8*)(qptr + s * 16);
    }

    const bf16* ksrc = qkv + NH * DH + kvh * DH;
    const bf16* vsrc = vt_g + (size_t)kvh * DH * S_LEN;
    const int kcK = lane & 15;
    const int krs = lane >> 4;
    const int kcV = lane & 7;
    const int vrs = lane >> 3;

    auto stage = [&](int buf, int kt) {
        const int k0s = kt * 64;
#pragma unroll
        for (int j = 0; j < 4; ++j) {
            int r = w * 16 + j * 4 + krs;
            load_lds16(ksrc + (size_t)(k0s + r) * QKV_N + ((kcK ^ (r & 7)) * 8),
                       &Ks[buf][(w * 16 + j * 4) * 128]);
        }
#pragma unroll
        for (int j = 0; j < 4; ++j) {
            int d = w * 32 + j * 8 + vrs;
            load_lds16(vsrc + (size_t)d * S_LEN + k0s + ((kcV ^ (d & 7)) * 8),
                       &Vt[buf][(w * 32 + j * 8) * 64]);
        }
    };

    f32x16 acc[4];
#pragma unroll
    for (int t = 0; t < 4; ++t)
#pragma unroll
        for (int r = 0; r < 16; ++r) acc[t][r] = 0.f;
    float m2 = -1e30f, l = 0.f;

    const int kt_last = (q0 + 127) >> 6;
    int buf = 0;
    stage(0, 0);
    __syncthreads();

    for (int kt = 0; kt <= kt_last; ++kt) {
        if (kt < kt_last) stage(buf ^ 1, kt + 1);
        const int k0 = kt * 64;
        if (k0 <= q0 + w * 32 + 31) {
            f32x16 st[2];
#pragma unroll
            for (int t = 0; t < 2; ++t)
#pragma unroll
                for (int r = 0; r < 16; ++r) st[t][r] = 0.f;
            const bf16* Kb = &Ks[buf][0];
            __builtin_amdgcn_s_setprio(1);
#pragma unroll
            for (int t = 0; t < 2; ++t) {
                const int key = t * 32 + ln;
#pragma unroll
                for (int s = 0; s < 8; ++s) {
                    bf16x8 kf =
                        *(const bf16x8*)&Kb[key * 128 + (((2 * s + hi) ^ (key & 7)) * 8)];
                    st[t] = mfma32(kf, qf[s], st[t]);
                }
            }
            __builtin_amdgcn_s_setprio(0);
            const bool needMask = (k0 + 63 > q0 + w * 32);
            float tmax = -1e30f;
#pragma unroll
            for (int t = 0; t < 2; ++t)
#pragma unroll
                for (int r = 0; r < 16; ++r) {
                    int kcol = k0 + t * 32 + (r & 3) + 8 * (r >> 2) + 4 * hi;
                    float v = st[t][r] * SCALE2_ATT;
                    if (needMask && kcol > qrow) v = -1e30f;
                    st[t][r] = v;
                    tmax = fmaxf(tmax, v);
                }
            tmax = fmaxf(tmax, __shfl_xor(tmax, 32, 64));
            float mnew = fmaxf(m2, tmax);
            float alpha = exp2f(m2 - mnew);
            float rs = 0.f;
#pragma unroll
            for (int t = 0; t < 2; ++t)
#pragma unroll
                for (int r = 0; r < 16; ++r) {
                    float e = exp2f(st[t][r] - mnew);
                    st[t][r] = e;
                    rs += e;
                }
            rs += __shfl_xor(rs, 32, 64);
            l = l * alpha + rs;
            m2 = mnew;
#pragma unroll
            for (int t = 0; t < 4; ++t)
#pragma unroll
                for (int r = 0; r < 16; ++r) acc[t][r] *= alpha;
            unsigned cw[16];
#pragma unroll
            for (int i = 0; i < 16; ++i)
                cw[i] = pack2_bf16(st[i >> 3][2 * (i & 7)], st[i >> 3][2 * (i & 7) + 1]);
            bf16x8 pa[4];
#pragma unroll
            for (int ks = 0; ks < 4; ++ks) {
                const int base = (ks >> 1) * 8 + (ks & 1) * 4;
                union { unsigned u[4]; bf16x8 v; } pk;
#pragma unroll
                for (int e = 0; e < 2; ++e) {
                    unsigned A = cw[base + e];
                    unsigned B = cw[base + 2 + e];
                    unsigned tA = (unsigned)__shfl_xor((int)A, 32, 64);
                    unsigned tB = (unsigned)__shfl_xor((int)B, 32, 64);
                    pk.u[e] = hi ? tB : A;
                    pk.u[e + 2] = hi ? B : tA;
                }
                pa[ks] = pk.v;
            }
            const bf16* Vb = &Vt[buf][0];
            __builtin_amdgcn_s_setprio(1);
#pragma unroll
            for (int dt = 0; dt < 4; ++dt) {
                const int d = dt * 32 + ln;
#pragma unroll
                for (int ks = 0; ks < 4; ++ks) {
                    bf16x8 vf =
                        *(const bf16x8*)&Vb[d * 64 + (((2 * ks + hi) ^ (d & 7)) * 8)];
                    acc[dt] = mfma32(vf, pa[ks], acc[dt]);
                }
            }
            __builtin_amdgcn_s_setprio(0);
        }
        __syncthreads();
        buf ^= 1;
    }

    const float invl = 1.f / l;
    bf16* outp = qkv + (size_t)qrow * QKV_N + hq * DH;
#pragma unroll
    for (int dt = 0; dt < 4; ++dt)
#pragma unroll
        for (int rq = 0; rq < 4; ++rq) {
            bf16x4 o;
#pragma unroll
            for (int i = 0; i < 4; ++i) o[i] = (bf16)(acc[dt][rq * 4 + i] * invl);
            *(bf16x4*)(outp + dt * 32 + rq * 8 + hi * 4) = o;
        }
}

extern "C" void kernel_launch(void* const* d_in, const int* in_sizes, int n_in,
                              void* d_out, int out_size, void* d_ws, size_t ws_size,
                              hipStream_t stream) {
    const int* positions = (const int*)d_in[0];
    const float* hidden = (const float*)d_in[1];
    const float* w_qkv = (const float*)d_in[2];
    const float* w_o = (const float*)d_in[3];
    float* out = (float*)d_out;

    const size_t n_qkv = (size_t)S_LEN * QKV_N;
    const size_t n_vt = (size_t)NKV * DH * S_LEN;
    const size_t n_hid = (size_t)S_LEN * HID;
    const size_t n_wqkv = (size_t)QKV_N * HID;
    const size_t n_wo = (size_t)HID * HID;

    const size_t need_min = (n_qkv + n_vt) * sizeof(bf16);
    const size_t need_full = (n_qkv + n_vt + n_hid + n_wqkv + n_wo) * sizeof(bf16);
    if (ws_size < need_min) return;

    bf16* qkv = (bf16*)d_ws;
    bf16* vt_g = qkv + n_qkv;
    bf16* hid_b = vt_g + n_vt;
    bf16* wqkv_b = hid_b + n_hid;
    bf16* wo_b = wqkv_b + n_wqkv;
    const bool full = ws_size >= need_full;

    if (full) {
        cvt_kernel<<<(int)(n_hid / 8 + 255) / 256, 256, 0, stream>>>(hidden, hid_b, (int)(n_hid / 8));
        cvt_kernel<<<(int)(n_wqkv / 8 + 255) / 256, 256, 0, stream>>>(w_qkv, wqkv_b, (int)(n_wqkv / 8));
        cvt_kernel<<<(int)(n_wo / 8 + 255) / 256, 256, 0, stream>>>(w_o, wo_b, (int)(n_wo / 8));
        hipFuncSetAttribute(reinterpret_cast<const void*>(&gemm_8ph<256, bf16>),
                            hipFuncAttributeMaxDynamicSharedMemorySize, 131072);
        gemm_8ph<256, bf16><<<dim3(QKV_N / 256, S_LEN / 256), 512, 131072, stream>>>(
            hid_b, wqkv_b, qkv, HID, HID, QKV_N);
    } else {
        gemm_bt<<<dim3(QKV_N / 128, S_LEN / 128), 256, 0, stream>>>(hidden, w_qkv, qkv, HID, HID, QKV_N);
    }
    const int total = S_LEN * (NH + NKV) * 64;
    rope_kernel<<<(total + 255) / 256, 256, 0, stream>>>(qkv, positions);
    vtrans_kernel<<<dim3(S_LEN / 64, NKV), 256, 0, stream>>>(qkv, vt_g);
    attn_kernel<<<dim3(NH, S_LEN / 128), 256, 0, stream>>>(qkv, vt_g);
    if (full) {
        hipFuncSetAttribute(reinterpret_cast<const void*>(&gemm_8ph<128, float>),
                            hipFuncAttributeMaxDynamicSharedMemorySize, 98304);
        gemm_8ph<128, float><<<dim3(HID / 128, S_LEN / 256), 512, 98304, stream>>>(
            qkv, wo_b, out, HID, QKV_N, HID);
    } else {
        gemm_bt<<<dim3(HID / 128, S_LEN / 128), 256, 0, stream>>>(qkv, w_o, out, HID, QKV_N, HID);
    }
}

// Round 4
// 572.596 us; speedup vs baseline: 1.0071x; 1.0071x over previous
//
#include <hip/hip_runtime.h>
#include <hip/hip_bf16.h>

#define S_LEN 2048
#define HID 4096
#define NH 32
#define NKV 8
#define DH 128
#define QKV_N ((NH + 2 * NKV) * DH) /* 6144 */
#define SCALE_ATT 0.08838834764831845f /* 128^-0.5 */
#define SCALE2_ATT 0.12751744f         /* SCALE_ATT * log2(e) */

typedef __bf16 bf16;
typedef __bf16 bf16x8 __attribute__((ext_vector_type(8)));
typedef __bf16 bf16x4 __attribute__((ext_vector_type(4)));
typedef float f32x4 __attribute__((ext_vector_type(4)));
typedef float f32x16 __attribute__((ext_vector_type(16)));

__device__ inline f32x4 mfma16(bf16x8 a, bf16x8 b, f32x4 c) {
    return __builtin_amdgcn_mfma_f32_16x16x32_bf16(a, b, c, 0, 0, 0);
}
__device__ inline f32x16 mfma32(bf16x8 a, bf16x8 b, f32x16 c) {
    return __builtin_amdgcn_mfma_f32_32x32x16_bf16(a, b, c, 0, 0, 0);
}

__device__ inline bf16x8 load8(const float* p) {
    const float4 a = ((const float4*)p)[0];
    const float4 b = ((const float4*)p)[1];
    bf16x8 r;
    r[0] = (bf16)a.x; r[1] = (bf16)a.y; r[2] = (bf16)a.z; r[3] = (bf16)a.w;
    r[4] = (bf16)b.x; r[5] = (bf16)b.y; r[6] = (bf16)b.z; r[7] = (bf16)b.w;
    return r;
}
__device__ inline bf16x8 load8(const bf16* p) { return *(const bf16x8*)p; }

// direct global->LDS DMA, 16 bytes/lane. LDS dest is wave-uniform base + lane*16.
__device__ inline void load_lds16(const bf16* g, bf16* lds_base) {
    __builtin_amdgcn_global_load_lds(
        (const __attribute__((address_space(1))) void*)g,
        (__attribute__((address_space(3))) void*)lds_base, 16, 0, 0);
}

// pack 2 f32 -> 1 u32 holding 2 bf16
__device__ inline unsigned pack2_bf16(float lo, float hi) {
    union { bf16 h[2]; unsigned u; } r;
    r.h[0] = (bf16)lo;
    r.h[1] = (bf16)hi;
    return r.u;
}

// fused fp32 -> bf16 bulk convert for three buffers (one launch)
__global__ __launch_bounds__(256) void cvt3_kernel(const float* __restrict__ s0, bf16* __restrict__ d0, int c0,
                                                   const float* __restrict__ s1, bf16* __restrict__ d1, int c1,
                                                   const float* __restrict__ s2, bf16* __restrict__ d2, int c2) {
    int i = blockIdx.x * 256 + threadIdx.x;
    if (i < c0) { *(bf16x8*)&d0[(size_t)i * 8] = load8(&s0[(size_t)i * 8]); return; }
    i -= c0;
    if (i < c1) { *(bf16x8*)&d1[(size_t)i * 8] = load8(&s1[(size_t)i * 8]); return; }
    i -= c1;
    if (i < c2) { *(bf16x8*)&d2[(size_t)i * 8] = load8(&s2[(size_t)i * 8]); }
}

// ---------------------------------------------------------------------------
// 256-row-tile GEMM with counted-vmcnt pipeline (T3/T4/T5 + T2 swizzle).
// C[M x N] = A[M x K] @ B[N x K]^T, bf16 in. BM=256, BN=256 or 128, BK=64.
// 512 threads = 8 waves (2 M x 4 N), per-wave tile 128 x (BN/4), 32x32x16 MFMA.
// LDS double-buffered; per iter: issue next-tile global_load_lds into the
// other buffer, THEN s_waitcnt vmcnt(8|6) (counted - next tile's loads stay
// in flight across both barriers and all MFMA), raw s_barrier, compute.
// Tile->block mapping: NATURAL order. gridDim.x % 8 == 0 so XCD = bx % 8:
// each XCD owns gridDim.x/8 B-panels shared by all its resident blocks
// (B fetched ~once per XCD); A (small) is the cross-XCD-duplicated matrix.
// (Round-3 row-stripe swizzle streamed all of B per XCD: FETCH 205 MB.)
// ---------------------------------------------------------------------------
template <int BN, typename OutT>
__global__ __launch_bounds__(512, 2) void gemm_8ph(const bf16* __restrict__ A,
                                                   const bf16* __restrict__ B,
                                                   OutT* __restrict__ C,
                                                   int K, int lda, int ldc) {
    constexpr int WTN = BN / 4;     // per-wave N extent
    constexpr int NREP = WTN / 32;  // 32-wide frags per wave (2 or 1)
    constexpr int BLOADS = BN / 64; // B stage calls per wave (4 or 2)
    extern __shared__ char smem[];
    bf16* As = (bf16*)smem;                       // [2][256*64]
    bf16* Bs = (bf16*)(smem + 2 * 256 * 64 * 2);  // [2][BN*64]

    const int tid = threadIdx.x;
    const int lane = tid & 63;
    const int w = tid >> 6;     // 0..7
    const int wm = w >> 2;      // 0..1
    const int wn = w & 3;       // 0..3
    const int ln = lane & 31;
    const int hi = lane >> 5;
    const int rseg = lane >> 3; // row within 8-row staging group
    const int gc = (lane & 7) ^ rseg; // swizzled source chunk

    const int m0 = (int)blockIdx.y * 256;
    const int n0 = (int)blockIdx.x * BN;

    const int NT = K >> 6;

    auto stage = [&](int b, int kt) {
        const int k0 = kt * 64;
        const bf16* Ag = &A[(size_t)(m0 + w * 32 + rseg) * lda + k0 + gc * 8];
        bf16* Al = &As[b * (256 * 64) + (w * 32) * 64];
#pragma unroll
        for (int j = 0; j < 4; ++j)
            load_lds16(Ag + (size_t)j * 8 * lda, Al + j * 512);
        const bf16* Bg = &B[(size_t)(n0 + w * (BN / 8) + rseg) * K + k0 + gc * 8];
        bf16* Bl = &Bs[b * (BN * 64) + (w * (BN / 8)) * 64];
#pragma unroll
        for (int j = 0; j < BLOADS; ++j)
            load_lds16(Bg + (size_t)j * 8 * K, Bl + j * 512);
    };

    f32x16 acc[4][NREP];
#pragma unroll
    for (int mi = 0; mi < 4; ++mi)
#pragma unroll
        for (int j = 0; j < NREP; ++j)
#pragma unroll
            for (int r = 0; r < 16; ++r) acc[mi][j][r] = 0.f;

    stage(0, 0);
    int buf = 0;
    for (int kt = 0; kt < NT; ++kt) {
        if (kt + 1 < NT) {
            stage(buf ^ 1, kt + 1); // next tile DMA: stays in flight across barriers
            if constexpr (BN == 256)
                asm volatile("s_waitcnt vmcnt(8)" ::: "memory"); // my current-tile loads landed
            else
                asm volatile("s_waitcnt vmcnt(6)" ::: "memory");
        } else {
            asm volatile("s_waitcnt vmcnt(0)" ::: "memory");
        }
        __builtin_amdgcn_s_barrier(); // everyone's current-tile DMA landed
        __builtin_amdgcn_sched_barrier(0);

        const bf16* Ab = &As[buf * (256 * 64)];
        const bf16* Bb = &Bs[buf * (BN * 64)];
        bf16x8 bfr[NREP][4];
#pragma unroll
        for (int j = 0; j < NREP; ++j)
#pragma unroll
            for (int kk = 0; kk < 4; ++kk) {
                const int n = wn * WTN + j * 32 + ln;
                bfr[j][kk] = *(const bf16x8*)&Bb[n * 64 + (((2 * kk + hi) ^ (ln & 7)) * 8)];
            }
#pragma unroll
        for (int p = 0; p < 2; ++p) {
            bf16x8 af[2][4];
#pragma unroll
            for (int i = 0; i < 2; ++i)
#pragma unroll
                for (int kk = 0; kk < 4; ++kk) {
                    const int m = wm * 128 + (p * 2 + i) * 32 + ln;
                    af[i][kk] = *(const bf16x8*)&Ab[m * 64 + (((2 * kk + hi) ^ (ln & 7)) * 8)];
                }
            __builtin_amdgcn_s_setprio(1);
#pragma unroll
            for (int i = 0; i < 2; ++i)
#pragma unroll
                for (int j = 0; j < NREP; ++j)
#pragma unroll
                    for (int kk = 0; kk < 4; ++kk)
                        acc[p * 2 + i][j] = mfma32(af[i][kk], bfr[j][kk], acc[p * 2 + i][j]);
            __builtin_amdgcn_s_setprio(0);
        }
        __builtin_amdgcn_sched_barrier(0);
        asm volatile("s_waitcnt lgkmcnt(0)" ::: "memory"); // my LDS reads complete
        __builtin_amdgcn_s_barrier(); // all reads of buf done -> next iter may overwrite
        __builtin_amdgcn_sched_barrier(0);
        buf ^= 1;
    }

    // epilogue: C[row][col], row from A-frag index, col = ln (attn-verified map)
#pragma unroll
    for (int mi = 0; mi < 4; ++mi)
#pragma unroll
        for (int j = 0; j < NREP; ++j)
#pragma unroll
            for (int r = 0; r < 16; ++r) {
                int row = m0 + wm * 128 + mi * 32 + (r & 3) + 8 * (r >> 2) + 4 * hi;
                int col = n0 + wn * WTN + j * 32 + ln;
                C[(size_t)row * ldc + col] = (OutT)acc[mi][j][r];
            }
}

// ---------------- fallback fp32-staging GEMM (low-workspace path) ----------------
template <typename AT, typename OutT>
__global__ __launch_bounds__(256) void gemm_bt(const AT* __restrict__ A,
                                               const float* __restrict__ B,
                                               OutT* __restrict__ C,
                                               int K, int lda, int ldc) {
    const int tid = threadIdx.x;
    const int lane = tid & 63;
    const int w = tid >> 6;
    const int m0 = blockIdx.y * 128;
    const int n0 = blockIdx.x * 128;
    const int wm = (w >> 1) * 64;
    const int wn = (w & 1) * 64;
    const int ln = lane & 15;
    const int qo = lane >> 4;

    __shared__ bf16 As[128 * 72];
    __shared__ bf16 Bs[128 * 72];

    f32x4 acc[4][4];
#pragma unroll
    for (int mi = 0; mi < 4; ++mi)
#pragma unroll
        for (int ni = 0; ni < 4; ++ni) acc[mi][ni] = f32x4{0.f, 0.f, 0.f, 0.f};

    for (int k0 = 0; k0 < K; k0 += 64) {
#pragma unroll
        for (int i = 0; i < 4; ++i) {
            int v = tid + i * 256;
            int row = v >> 3;
            int col = (v & 7) * 8;
            *(bf16x8*)&As[row * 72 + col] = load8(&A[(size_t)(m0 + row) * lda + k0 + col]);
            *(bf16x8*)&Bs[row * 72 + col] = load8(&B[(size_t)(n0 + row) * K + k0 + col]);
        }
        __syncthreads();
#pragma unroll
        for (int kk = 0; kk < 64; kk += 32) {
            bf16x8 af[4], bfr[4];
#pragma unroll
            for (int mi = 0; mi < 4; ++mi)
                af[mi] = *(const bf16x8*)&As[(wm + mi * 16 + ln) * 72 + kk + qo * 8];
#pragma unroll
            for (int ni = 0; ni < 4; ++ni)
                bfr[ni] = *(const bf16x8*)&Bs[(wn + ni * 16 + ln) * 72 + kk + qo * 8];
#pragma unroll
            for (int mi = 0; mi < 4; ++mi)
#pragma unroll
                for (int ni = 0; ni < 4; ++ni)
                    acc[mi][ni] = mfma16(af[mi], bfr[ni], acc[mi][ni]);
        }
        __syncthreads();
    }
#pragma unroll
    for (int mi = 0; mi < 4; ++mi)
#pragma unroll
        for (int ni = 0; ni < 4; ++ni)
#pragma unroll
            for (int r = 0; r < 4; ++r) {
                int row = m0 + wm + mi * 16 + qo * 4 + r;
                int col = n0 + wn + ni * 16 + ln;
                C[(size_t)row * ldc + col] = (OutT)acc[mi][ni][r];
            }
}

// RoPE in-place on bf16 qkv buffer
__global__ __launch_bounds__(256) void rope_kernel(bf16* __restrict__ qkv,
                                                   const int* __restrict__ positions) {
    int idx = blockIdx.x * 256 + threadIdx.x;
    const int total = S_LEN * (NH + NKV) * 64;
    if (idx >= total) return;
    int d = idx & 63;
    int t = idx >> 6;
    int head = t % (NH + NKV);
    int s = t / (NH + NKV);
    size_t base = (size_t)s * QKV_N + (head < NH ? head * DH : NH * DH + (head - NH) * DH);
    float x1 = (float)qkv[base + d];
    float x2 = (float)qkv[base + d + 64];
    float pos = (float)positions[s];
    float inv = expf(-0.21586735246819178f * (float)d);
    float ang = pos * inv;
    float c = cosf(ang);
    float sn = sinf(ang);
    qkv[base + d] = (bf16)(x1 * c - x2 * sn);
    qkv[base + d + 64] = (bf16)(x2 * c + x1 * sn);
}

// Pre-transpose V into vt_g[kvh][d][s]
__global__ __launch_bounds__(256) void vtrans_kernel(const bf16* __restrict__ qkv,
                                                     bf16* __restrict__ vt_g) {
    const int tid = threadIdx.x;
    const int s0 = blockIdx.x * 64;
    const int kvh = blockIdx.y;
    __shared__ bf16 Ls[64 * 136];
#pragma unroll
    for (int i = 0; i < 4; ++i) {
        int v = tid + i * 256;
        int row = v >> 4;
        int col = (v & 15) * 8;
        *(bf16x8*)&Ls[row * 136 + col] =
            *(const bf16x8*)&qkv[(size_t)(s0 + row) * QKV_N + (NH + NKV) * DH + kvh * DH + col];
    }
    __syncthreads();
#pragma unroll
    for (int i = 0; i < 4; ++i) {
        int u = tid + i * 256;
        int d = u >> 3;
        int sg = (u & 7) * 8;
        bf16x8 r;
#pragma unroll
        for (int j = 0; j < 8; ++j) r[j] = Ls[(sg + j) * 136 + d];
        *(bf16x8*)&vt_g[((size_t)kvh * DH + d) * S_LEN + s0 + sg] = r;
    }
}

// ---------------------------------------------------------------------------
// Flash attention (round-2 proven): 4 warps x 32 q-rows, KVBLK=64, 32x32x16
// MFMA, swapped QK^T, in-register softmax, shfl cross-half P exchange,
// O^T = Vt @ P^T, XOR-swizzled LDS via global_load_lds, 1 barrier/tile.
// ---------------------------------------------------------------------------
__global__ __launch_bounds__(256) void attn_kernel(bf16* __restrict__ qkv,
                                                   const bf16* __restrict__ vt_g) {
    const int tid = threadIdx.x;
    const int lane = tid & 63;
    const int w = tid >> 6;
    const int ln = lane & 31;
    const int hi = lane >> 5;
    const int hq = blockIdx.x;
    const int qtile = (int)gridDim.y - 1 - (int)blockIdx.y; // heavy first
    const int kvh = hq >> 2;
    const int q0 = qtile * 128;
    const int qrow = q0 + w * 32 + ln;

    __shared__ __align__(128) bf16 Ks[2][64 * 128];
    __shared__ __align__(128) bf16 Vt[2][128 * 64];

    bf16x8 qf[8];
    {
        const bf16* qptr = qkv + (size_t)qrow * QKV_N + hq * DH + hi * 8;
#pragma unroll
        for (int s = 0; s < 8; ++s) qf[s] = *(const bf16x8*)(qptr + s * 16);
    }

    const bf16* ksrc = qkv + NH * DH + kvh * DH;
    const bf16* vsrc = vt_g + (size_t)kvh * DH * S_LEN;
    const int kcK = lane & 15;
    const int krs = lane >> 4;
    const int kcV = lane & 7;
    const int vrs = lane >> 3;

    auto stage = [&](int buf, int kt) {
        const int k0s = kt * 64;
#pragma unroll
        for (int j = 0; j < 4; ++j) {
            int r = w * 16 + j * 4 + krs;
            load_lds16(ksrc + (size_t)(k0s + r) * QKV_N + ((kcK ^ (r & 7)) * 8),
                       &Ks[buf][(w * 16 + j * 4) * 128]);
        }
#pragma unroll
        for (int j = 0; j < 4; ++j) {
            int d = w * 32 + j * 8 + vrs;
            load_lds16(vsrc + (size_t)d * S_LEN + k0s + ((kcV ^ (d & 7)) * 8),
                       &Vt[buf][(w * 32 + j * 8) * 64]);
        }
    };

    f32x16 acc[4];
#pragma unroll
    for (int t = 0; t < 4; ++t)
#pragma unroll
        for (int r = 0; r < 16; ++r) acc[t][r] = 0.f;
    float m2 = -1e30f, l = 0.f;

    const int kt_last = (q0 + 127) >> 6;
    int buf = 0;
    stage(0, 0);
    __syncthreads();

    for (int kt = 0; kt <= kt_last; ++kt) {
        if (kt < kt_last) stage(buf ^ 1, kt + 1);
        const int k0 = kt * 64;
        if (k0 <= q0 + w * 32 + 31) {
            f32x16 st[2];
#pragma unroll
            for (int t = 0; t < 2; ++t)
#pragma unroll
                for (int r = 0; r < 16; ++r) st[t][r] = 0.f;
            const bf16* Kb = &Ks[buf][0];
            __builtin_amdgcn_s_setprio(1);
#pragma unroll
            for (int t = 0; t < 2; ++t) {
                const int key = t * 32 + ln;
#pragma unroll
                for (int s = 0; s < 8; ++s) {
                    bf16x8 kf =
                        *(const bf16x8*)&Kb[key * 128 + (((2 * s + hi) ^ (key & 7)) * 8)];
                    st[t] = mfma32(kf, qf[s], st[t]);
                }
            }
            __builtin_amdgcn_s_setprio(0);
            const bool needMask = (k0 + 63 > q0 + w * 32);
            float tmax = -1e30f;
#pragma unroll
            for (int t = 0; t < 2; ++t)
#pragma unroll
                for (int r = 0; r < 16; ++r) {
                    int kcol = k0 + t * 32 + (r & 3) + 8 * (r >> 2) + 4 * hi;
                    float v = st[t][r] * SCALE2_ATT;
                    if (needMask && kcol > qrow) v = -1e30f;
                    st[t][r] = v;
                    tmax = fmaxf(tmax, v);
                }
            tmax = fmaxf(tmax, __shfl_xor(tmax, 32, 64));
            float mnew = fmaxf(m2, tmax);
            float alpha = exp2f(m2 - mnew);
            float rs = 0.f;
#pragma unroll
            for (int t = 0; t < 2; ++t)
#pragma unroll
                for (int r = 0; r < 16; ++r) {
                    float e = exp2f(st[t][r] - mnew);
                    st[t][r] = e;
                    rs += e;
                }
            rs += __shfl_xor(rs, 32, 64);
            l = l * alpha + rs;
            m2 = mnew;
#pragma unroll
            for (int t = 0; t < 4; ++t)
#pragma unroll
                for (int r = 0; r < 16; ++r) acc[t][r] *= alpha;
            unsigned cw[16];
#pragma unroll
            for (int i = 0; i < 16; ++i)
                cw[i] = pack2_bf16(st[i >> 3][2 * (i & 7)], st[i >> 3][2 * (i & 7) + 1]);
            bf16x8 pa[4];
#pragma unroll
            for (int ks = 0; ks < 4; ++ks) {
                const int base = (ks >> 1) * 8 + (ks & 1) * 4;
                union { unsigned u[4]; bf16x8 v; } pk;
#pragma unroll
                for (int e = 0; e < 2; ++e) {
                    unsigned A = cw[base + e];
                    unsigned B = cw[base + 2 + e];
                    unsigned tA = (unsigned)__shfl_xor((int)A, 32, 64);
                    unsigned tB = (unsigned)__shfl_xor((int)B, 32, 64);
                    pk.u[e] = hi ? tB : A;
                    pk.u[e + 2] = hi ? B : tA;
                }
                pa[ks] = pk.v;
            }
            const bf16* Vb = &Vt[buf][0];
            __builtin_amdgcn_s_setprio(1);
#pragma unroll
            for (int dt = 0; dt < 4; ++dt) {
                const int d = dt * 32 + ln;
#pragma unroll
                for (int ks = 0; ks < 4; ++ks) {
                    bf16x8 vf =
                        *(const bf16x8*)&Vb[d * 64 + (((2 * ks + hi) ^ (d & 7)) * 8)];
                    acc[dt] = mfma32(vf, pa[ks], acc[dt]);
                }
            }
            __builtin_amdgcn_s_setprio(0);
        }
        __syncthreads();
        buf ^= 1;
    }

    const float invl = 1.f / l;
    bf16* outp = qkv + (size_t)qrow * QKV_N + hq * DH;
#pragma unroll
    for (int dt = 0; dt < 4; ++dt)
#pragma unroll
        for (int rq = 0; rq < 4; ++rq) {
            bf16x4 o;
#pragma unroll
            for (int i = 0; i < 4; ++i) o[i] = (bf16)(acc[dt][rq * 4 + i] * invl);
            *(bf16x4*)(outp + dt * 32 + rq * 8 + hi * 4) = o;
        }
}

extern "C" void kernel_launch(void* const* d_in, const int* in_sizes, int n_in,
                              void* d_out, int out_size, void* d_ws, size_t ws_size,
                              hipStream_t stream) {
    const int* positions = (const int*)d_in[0];
    const float* hidden = (const float*)d_in[1];
    const float* w_qkv = (const float*)d_in[2];
    const float* w_o = (const float*)d_in[3];
    float* out = (float*)d_out;

    const size_t n_qkv = (size_t)S_LEN * QKV_N;
    const size_t n_vt = (size_t)NKV * DH * S_LEN;
    const size_t n_hid = (size_t)S_LEN * HID;
    const size_t n_wqkv = (size_t)QKV_N * HID;
    const size_t n_wo = (size_t)HID * HID;

    const size_t need_min = (n_qkv + n_vt) * sizeof(bf16);
    const size_t need_full = (n_qkv + n_vt + n_hid + n_wqkv + n_wo) * sizeof(bf16);
    if (ws_size < need_min) return;

    bf16* qkv = (bf16*)d_ws;
    bf16* vt_g = qkv + n_qkv;
    bf16* hid_b = vt_g + n_vt;
    bf16* wqkv_b = hid_b + n_hid;
    bf16* wo_b = wqkv_b + n_wqkv;
    const bool full = ws_size >= need_full;

    if (full) {
        const int c0 = (int)(n_hid / 8), c1 = (int)(n_wqkv / 8), c2 = (int)(n_wo / 8);
        cvt3_kernel<<<(c0 + c1 + c2 + 255) / 256, 256, 0, stream>>>(hidden, hid_b, c0,
                                                                    w_qkv, wqkv_b, c1,
                                                                    w_o, wo_b, c2);
        hipFuncSetAttribute(reinterpret_cast<const void*>(&gemm_8ph<256, bf16>),
                            hipFuncAttributeMaxDynamicSharedMemorySize, 131072);
        gemm_8ph<256, bf16><<<dim3(QKV_N / 256, S_LEN / 256), 512, 131072, stream>>>(
            hid_b, wqkv_b, qkv, HID, HID, QKV_N);
    } else {
        gemm_bt<<<dim3(QKV_N / 128, S_LEN / 128), 256, 0, stream>>>(hidden, w_qkv, qkv, HID, HID, QKV_N);
    }
    const int total = S_LEN * (NH + NKV) * 64;
    rope_kernel<<<(total + 255) / 256, 256, 0, stream>>>(qkv, positions);
    vtrans_kernel<<<dim3(S_LEN / 64, NKV), 256, 0, stream>>>(qkv, vt_g);
    attn_kernel<<<dim3(NH, S_LEN / 128), 256, 0, stream>>>(qkv, vt_g);
    if (full) {
        hipFuncSetAttribute(reinterpret_cast<const void*>(&gemm_8ph<128, float>),
                            hipFuncAttributeMaxDynamicSharedMemorySize, 98304);
        gemm_8ph<128, float><<<dim3(HID / 128, S_LEN / 256), 512, 98304, stream>>>(
            qkv, wo_b, out, HID, QKV_N, HID);
    } else {
        gemm_bt<<<dim3(HID / 128, S_LEN / 128), 256, 0, stream>>>(qkv, w_o, out, HID, QKV_N, HID);
    }
}

// Round 5
// 537.152 us; speedup vs baseline: 1.0735x; 1.0660x over previous
//
#include <hip/hip_runtime.h>
#include <hip/hip_bf16.h>

#define S_LEN 2048
#define HID 4096
#define NH 32
#define NKV 8
#define DH 128
#define QKV_N ((NH + 2 * NKV) * DH) /* 6144 */
#define SCALE_ATT 0.08838834764831845f /* 128^-0.5 */
#define SCALE2_ATT 0.12751744f         /* SCALE_ATT * log2(e) */

typedef __bf16 bf16;
typedef __bf16 bf16x8 __attribute__((ext_vector_type(8)));
typedef __bf16 bf16x4 __attribute__((ext_vector_type(4)));
typedef float f32x4 __attribute__((ext_vector_type(4)));
typedef float f32x16 __attribute__((ext_vector_type(16)));

__device__ inline f32x4 mfma16(bf16x8 a, bf16x8 b, f32x4 c) {
    return __builtin_amdgcn_mfma_f32_16x16x32_bf16(a, b, c, 0, 0, 0);
}
__device__ inline f32x16 mfma32(bf16x8 a, bf16x8 b, f32x16 c) {
    return __builtin_amdgcn_mfma_f32_32x32x16_bf16(a, b, c, 0, 0, 0);
}

__device__ inline bf16x8 load8(const float* p) {
    const float4 a = ((const float4*)p)[0];
    const float4 b = ((const float4*)p)[1];
    bf16x8 r;
    r[0] = (bf16)a.x; r[1] = (bf16)a.y; r[2] = (bf16)a.z; r[3] = (bf16)a.w;
    r[4] = (bf16)b.x; r[5] = (bf16)b.y; r[6] = (bf16)b.z; r[7] = (bf16)b.w;
    return r;
}
__device__ inline bf16x8 load8(const bf16* p) { return *(const bf16x8*)p; }

// direct global->LDS DMA, 16 bytes/lane. LDS dest is wave-uniform base + lane*16.
__device__ inline void load_lds16(const bf16* g, bf16* lds_base) {
    __builtin_amdgcn_global_load_lds(
        (const __attribute__((address_space(1))) void*)g,
        (__attribute__((address_space(3))) void*)lds_base, 16, 0, 0);
}

// pack 2 f32 -> 1 u32 holding 2 bf16
__device__ inline unsigned pack2_bf16(float lo, float hi) {
    union { bf16 h[2]; unsigned u; } r;
    r.h[0] = (bf16)lo;
    r.h[1] = (bf16)hi;
    return r.u;
}

// fused fp32 -> bf16 bulk convert for three buffers (one launch)
__global__ __launch_bounds__(256) void cvt3_kernel(const float* __restrict__ s0, bf16* __restrict__ d0, int c0,
                                                   const float* __restrict__ s1, bf16* __restrict__ d1, int c1,
                                                   const float* __restrict__ s2, bf16* __restrict__ d2, int c2) {
    int i = blockIdx.x * 256 + threadIdx.x;
    if (i < c0) { *(bf16x8*)&d0[(size_t)i * 8] = load8(&s0[(size_t)i * 8]); return; }
    i -= c0;
    if (i < c1) { *(bf16x8*)&d1[(size_t)i * 8] = load8(&s1[(size_t)i * 8]); return; }
    i -= c1;
    if (i < c2) { *(bf16x8*)&d2[(size_t)i * 8] = load8(&s2[(size_t)i * 8]); }
}

// ---------------------------------------------------------------------------
// 256-row-tile GEMM, fine-grained 4-phase/K-tile schedule (m201-style).
// C[M x N] = A[M x K] @ B[N x K]^T, bf16 in. BM=256, BN in {256,128}, BK=64.
// 512 threads = 8 waves (2M x 4N), per-wave output 128 x BN/4, 32x32x16 MFMA.
// Per K-tile u (parity p), 4 phases (q = C-quadrant, 32 M-rows each):
//   ph0: ds_read all B-frags + A-q0 | stage A_{u+1} h0 -> p^1
//   ph1: ds_read A-q1              | stage A_{u+1} h1 -> p^1
//   ph2: ds_read A-q2              | stage B_{u+2} h0 -> p   (B slots free
//   ph3: ds_read A-q3              | stage B_{u+2} h1 -> p    after ph0 reads)
//   each phase: barrier; lgkmcnt(0)+sched_barrier; setprio(1) MFMA setprio(0);
//   [ph3: s_waitcnt vmcnt(4|2) = next tile's A landed, B halves in flight];
//   barrier.
// All write-after-read hazards are barrier-ordered (no racing DMA): A-halves
// land in the parity the PREVIOUS tile finished; B-halves land in slots whose
// only reads happened in ph0 of the current tile. vmcnt never drains to 0 in
// the main loop (T4); staging spread 1 half-tile/phase avoids the round-4
// burst-write/read LDS crosstalk (9.4M conflict cycles).
// LDS chunk-XOR swizzle identical to the proven 0-conflict kernels.
// ---------------------------------------------------------------------------
template <int BN, typename OutT>
__global__ __launch_bounds__(512, 2) void gemm_8ph(const bf16* __restrict__ A,
                                                   const bf16* __restrict__ B,
                                                   OutT* __restrict__ C,
                                                   int K, int lda, int ldc) {
    constexpr int WTN = BN / 4;     // per-wave N extent
    constexpr int NREP = WTN / 32;  // 32-wide frags per wave (2 or 1)
    extern __shared__ char smem[];
    bf16* As = (bf16*)smem;                       // [2][256*64]
    bf16* Bs = (bf16*)(smem + 2 * 256 * 64 * 2);  // [2][BN*64]

    const int tid = threadIdx.x;
    const int lane = tid & 63;
    const int w = tid >> 6;     // 0..7
    const int wm = w >> 2;      // 0..1
    const int wn = w & 3;       // 0..3
    const int ln = lane & 31;
    const int hi = lane >> 5;
    const int rseg = lane >> 3;       // row within 8-row staging group
    const int gc = (lane & 7) ^ rseg; // swizzled source chunk

    const int m0 = (int)blockIdx.y * 256;
    const int n0 = (int)blockIdx.x * BN;
    const int NT = K >> 6;

    // stage A half h (128 rows) of k-tile kt into parity pb: 2 DMA calls
    auto stageA = [&](int pb, int kt, int h) {
        const int k0 = kt * 64;
        const int rb = h * 128 + w * 16;
        const bf16* src = &A[(size_t)(m0 + rb + rseg) * lda + k0 + gc * 8];
        bf16* dst = &As[pb * (256 * 64) + rb * 64];
        load_lds16(src, dst);
        load_lds16(src + (size_t)8 * lda, dst + 8 * 64);
    };
    // stage B half h of k-tile kt into parity pb: 2 calls (BN=256) or 1 (BN=128)
    auto stageB = [&](int pb, int kt, int h) {
        const int k0 = kt * 64;
        if constexpr (BN == 256) {
            const int rb = h * 128 + w * 16;
            const bf16* src = &B[(size_t)(n0 + rb + rseg) * K + k0 + gc * 8];
            bf16* dst = &Bs[pb * (BN * 64) + rb * 64];
            load_lds16(src, dst);
            load_lds16(src + (size_t)8 * K, dst + 8 * 64);
        } else {
            const int rb = h * 64 + w * 8;
            const bf16* src = &B[(size_t)(n0 + rb + rseg) * K + k0 + gc * 8];
            bf16* dst = &Bs[pb * (BN * 64) + rb * 64];
            load_lds16(src, dst);
        }
    };

    f32x16 acc[4][NREP];
#pragma unroll
    for (int mi = 0; mi < 4; ++mi)
#pragma unroll
        for (int j = 0; j < NREP; ++j)
#pragma unroll
            for (int r = 0; r < 16; ++r) acc[mi][j][r] = 0.f;

    // prologue: B_0, A_0 -> parity 0; B_1 -> parity 1 (stream order = steady state)
    stageB(0, 0, 0); stageB(0, 0, 1);
    stageA(0, 0, 0); stageA(0, 0, 1);
    {
        const int k1 = NT > 1 ? 1 : 0;
        stageB(1, k1, 0); stageB(1, k1, 1);
    }
    if constexpr (BN == 256)
        asm volatile("s_waitcnt vmcnt(4)" ::: "memory"); // B_0 + A_0 landed
    else
        asm volatile("s_waitcnt vmcnt(2)" ::: "memory");
    __builtin_amdgcn_s_barrier();

    int p = 0;
    for (int u = 0; u < NT; ++u, p ^= 1) {
        const bf16* Ab = &As[p * (256 * 64)];
        const bf16* Bb = &Bs[p * (BN * 64)];
        const int ktA = u + 1 < NT ? u + 1 : NT - 1; // clamped re-stage (never read)
        const int ktB = u + 2 < NT ? u + 2 : NT - 1;
        bf16x8 bfr[NREP][4];
#pragma unroll
        for (int q = 0; q < 4; ++q) {
            if (q == 0) {
#pragma unroll
                for (int j = 0; j < NREP; ++j)
#pragma unroll
                    for (int kk = 0; kk < 4; ++kk) {
                        const int n = wn * WTN + j * 32 + ln;
                        bfr[j][kk] = *(const bf16x8*)&Bb[n * 64 + (((2 * kk + hi) ^ (ln & 7)) * 8)];
                    }
            }
            bf16x8 af[4];
#pragma unroll
            for (int kk = 0; kk < 4; ++kk) {
                const int m = wm * 128 + q * 32 + ln;
                af[kk] = *(const bf16x8*)&Ab[m * 64 + (((2 * kk + hi) ^ (ln & 7)) * 8)];
            }
            if (q == 0) stageA(p ^ 1, ktA, 0);
            else if (q == 1) stageA(p ^ 1, ktA, 1);
            else if (q == 2) stageB(p, ktB, 0);
            else stageB(p, ktB, 1);

            __builtin_amdgcn_s_barrier();
            asm volatile("s_waitcnt lgkmcnt(0)" ::: "memory");
            __builtin_amdgcn_sched_barrier(0);
            __builtin_amdgcn_s_setprio(1);
#pragma unroll
            for (int j = 0; j < NREP; ++j)
#pragma unroll
                for (int kk = 0; kk < 4; ++kk)
                    acc[q][j] = mfma32(af[kk], bfr[j][kk], acc[q][j]);
            __builtin_amdgcn_s_setprio(0);
            __builtin_amdgcn_sched_barrier(0);
            if (q == 3) {
                if constexpr (BN == 256)
                    asm volatile("s_waitcnt vmcnt(4)" ::: "memory"); // next tile's A+B(prev) landed
                else
                    asm volatile("s_waitcnt vmcnt(2)" ::: "memory");
            }
            __builtin_amdgcn_s_barrier();
        }
    }
    asm volatile("s_waitcnt vmcnt(0)" ::: "memory"); // drain clamped garbage stages

    // epilogue: C[row][col], row from A-frag index, col = ln (attn-verified map)
#pragma unroll
    for (int mi = 0; mi < 4; ++mi)
#pragma unroll
        for (int j = 0; j < NREP; ++j)
#pragma unroll
            for (int r = 0; r < 16; ++r) {
                int row = m0 + wm * 128 + mi * 32 + (r & 3) + 8 * (r >> 2) + 4 * hi;
                int col = n0 + wn * WTN + j * 32 + ln;
                C[(size_t)row * ldc + col] = (OutT)acc[mi][j][r];
            }
}

// ---------------- fallback fp32-staging GEMM (low-workspace path) ----------------
template <typename AT, typename OutT>
__global__ __launch_bounds__(256) void gemm_bt(const AT* __restrict__ A,
                                               const float* __restrict__ B,
                                               OutT* __restrict__ C,
                                               int K, int lda, int ldc) {
    const int tid = threadIdx.x;
    const int lane = tid & 63;
    const int w = tid >> 6;
    const int m0 = blockIdx.y * 128;
    const int n0 = blockIdx.x * 128;
    const int wm = (w >> 1) * 64;
    const int wn = (w & 1) * 64;
    const int ln = lane & 15;
    const int qo = lane >> 4;

    __shared__ bf16 As[128 * 72];
    __shared__ bf16 Bs[128 * 72];

    f32x4 acc[4][4];
#pragma unroll
    for (int mi = 0; mi < 4; ++mi)
#pragma unroll
        for (int ni = 0; ni < 4; ++ni) acc[mi][ni] = f32x4{0.f, 0.f, 0.f, 0.f};

    for (int k0 = 0; k0 < K; k0 += 64) {
#pragma unroll
        for (int i = 0; i < 4; ++i) {
            int v = tid + i * 256;
            int row = v >> 3;
            int col = (v & 7) * 8;
            *(bf16x8*)&As[row * 72 + col] = load8(&A[(size_t)(m0 + row) * lda + k0 + col]);
            *(bf16x8*)&Bs[row * 72 + col] = load8(&B[(size_t)(n0 + row) * K + k0 + col]);
        }
        __syncthreads();
#pragma unroll
        for (int kk = 0; kk < 64; kk += 32) {
            bf16x8 af[4], bfr[4];
#pragma unroll
            for (int mi = 0; mi < 4; ++mi)
                af[mi] = *(const bf16x8*)&As[(wm + mi * 16 + ln) * 72 + kk + qo * 8];
#pragma unroll
            for (int ni = 0; ni < 4; ++ni)
                bfr[ni] = *(const bf16x8*)&Bs[(wn + ni * 16 + ln) * 72 + kk + qo * 8];
#pragma unroll
            for (int mi = 0; mi < 4; ++mi)
#pragma unroll
                for (int ni = 0; ni < 4; ++ni)
                    acc[mi][ni] = mfma16(af[mi], bfr[ni], acc[mi][ni]);
        }
        __syncthreads();
    }
#pragma unroll
    for (int mi = 0; mi < 4; ++mi)
#pragma unroll
        for (int ni = 0; ni < 4; ++ni)
#pragma unroll
            for (int r = 0; r < 4; ++r) {
                int row = m0 + wm + mi * 16 + qo * 4 + r;
                int col = n0 + wn + ni * 16 + ln;
                C[(size_t)row * ldc + col] = (OutT)acc[mi][ni][r];
            }
}

// RoPE in-place on bf16 qkv buffer
__global__ __launch_bounds__(256) void rope_kernel(bf16* __restrict__ qkv,
                                                   const int* __restrict__ positions) {
    int idx = blockIdx.x * 256 + threadIdx.x;
    const int total = S_LEN * (NH + NKV) * 64;
    if (idx >= total) return;
    int d = idx & 63;
    int t = idx >> 6;
    int head = t % (NH + NKV);
    int s = t / (NH + NKV);
    size_t base = (size_t)s * QKV_N + (head < NH ? head * DH : NH * DH + (head - NH) * DH);
    float x1 = (float)qkv[base + d];
    float x2 = (float)qkv[base + d + 64];
    float pos = (float)positions[s];
    float inv = expf(-0.21586735246819178f * (float)d);
    float ang = pos * inv;
    float c = cosf(ang);
    float sn = sinf(ang);
    qkv[base + d] = (bf16)(x1 * c - x2 * sn);
    qkv[base + d + 64] = (bf16)(x2 * c + x1 * sn);
}

// Pre-transpose V into vt_g[kvh][d][s]
__global__ __launch_bounds__(256) void vtrans_kernel(const bf16* __restrict__ qkv,
                                                     bf16* __restrict__ vt_g) {
    const int tid = threadIdx.x;
    const int s0 = blockIdx.x * 64;
    const int kvh = blockIdx.y;
    __shared__ bf16 Ls[64 * 136];
#pragma unroll
    for (int i = 0; i < 4; ++i) {
        int v = tid + i * 256;
        int row = v >> 4;
        int col = (v & 15) * 8;
        *(bf16x8*)&Ls[row * 136 + col] =
            *(const bf16x8*)&qkv[(size_t)(s0 + row) * QKV_N + (NH + NKV) * DH + kvh * DH + col];
    }
    __syncthreads();
#pragma unroll
    for (int i = 0; i < 4; ++i) {
        int u = tid + i * 256;
        int d = u >> 3;
        int sg = (u & 7) * 8;
        bf16x8 r;
#pragma unroll
        for (int j = 0; j < 8; ++j) r[j] = Ls[(sg + j) * 136 + d];
        *(bf16x8*)&vt_g[((size_t)kvh * DH + d) * S_LEN + s0 + sg] = r;
    }
}

// ---------------------------------------------------------------------------
// Flash attention (round-2 proven): 4 warps x 32 q-rows, KVBLK=64, 32x32x16
// MFMA, swapped QK^T, in-register softmax, shfl cross-half P exchange,
// O^T = Vt @ P^T, XOR-swizzled LDS via global_load_lds, 1 barrier/tile.
// ---------------------------------------------------------------------------
__global__ __launch_bounds__(256) void attn_kernel(bf16* __restrict__ qkv,
                                                   const bf16* __restrict__ vt_g) {
    const int tid = threadIdx.x;
    const int lane = tid & 63;
    const int w = tid >> 6;
    const int ln = lane & 31;
    const int hi = lane >> 5;
    const int hq = blockIdx.x;
    const int qtile = (int)gridDim.y - 1 - (int)blockIdx.y; // heavy first
    const int kvh = hq >> 2;
    const int q0 = qtile * 128;
    const int qrow = q0 + w * 32 + ln;

    __shared__ __align__(128) bf16 Ks[2][64 * 128];
    __shared__ __align__(128) bf16 Vt[2][128 * 64];

    bf16x8 qf[8];
    {
        const bf16* qptr = qkv + (size_t)qrow * QKV_N + hq * DH + hi * 8;
#pragma unroll
        for (int s = 0; s < 8; ++s) qf[s] = *(const bf16x8*)(qptr + s * 16);
    }

    const bf16* ksrc = qkv + NH * DH + kvh * DH;
    const bf16* vsrc = vt_g + (size_t)kvh * DH * S_LEN;
    const int kcK = lane & 15;
    const int krs = lane >> 4;
    const int kcV = lane & 7;
    const int vrs = lane >> 3;

    auto stage = [&](int buf, int kt) {
        const int k0s = kt * 64;
#pragma unroll
        for (int j = 0; j < 4; ++j) {
            int r = w * 16 + j * 4 + krs;
            load_lds16(ksrc + (size_t)(k0s + r) * QKV_N + ((kcK ^ (r & 7)) * 8),
                       &Ks[buf][(w * 16 + j * 4) * 128]);
        }
#pragma unroll
        for (int j = 0; j < 4; ++j) {
            int d = w * 32 + j * 8 + vrs;
            load_lds16(vsrc + (size_t)d * S_LEN + k0s + ((kcV ^ (d & 7)) * 8),
                       &Vt[buf][(w * 32 + j * 8) * 64]);
        }
    };

    f32x16 acc[4];
#pragma unroll
    for (int t = 0; t < 4; ++t)
#pragma unroll
        for (int r = 0; r < 16; ++r) acc[t][r] = 0.f;
    float m2 = -1e30f, l = 0.f;

    const int kt_last = (q0 + 127) >> 6;
    int buf = 0;
    stage(0, 0);
    __syncthreads();

    for (int kt = 0; kt <= kt_last; ++kt) {
        if (kt < kt_last) stage(buf ^ 1, kt + 1);
        const int k0 = kt * 64;
        if (k0 <= q0 + w * 32 + 31) {
            f32x16 st[2];
#pragma unroll
            for (int t = 0; t < 2; ++t)
#pragma unroll
                for (int r = 0; r < 16; ++r) st[t][r] = 0.f;
            const bf16* Kb = &Ks[buf][0];
            __builtin_amdgcn_s_setprio(1);
#pragma unroll
            for (int t = 0; t < 2; ++t) {
                const int key = t * 32 + ln;
#pragma unroll
                for (int s = 0; s < 8; ++s) {
                    bf16x8 kf =
                        *(const bf16x8*)&Kb[key * 128 + (((2 * s + hi) ^ (key & 7)) * 8)];
                    st[t] = mfma32(kf, qf[s], st[t]);
                }
            }
            __builtin_amdgcn_s_setprio(0);
            const bool needMask = (k0 + 63 > q0 + w * 32);
            float tmax = -1e30f;
#pragma unroll
            for (int t = 0; t < 2; ++t)
#pragma unroll
                for (int r = 0; r < 16; ++r) {
                    int kcol = k0 + t * 32 + (r & 3) + 8 * (r >> 2) + 4 * hi;
                    float v = st[t][r] * SCALE2_ATT;
                    if (needMask && kcol > qrow) v = -1e30f;
                    st[t][r] = v;
                    tmax = fmaxf(tmax, v);
                }
            tmax = fmaxf(tmax, __shfl_xor(tmax, 32, 64));
            float mnew = fmaxf(m2, tmax);
            float alpha = exp2f(m2 - mnew);
            float rs = 0.f;
#pragma unroll
            for (int t = 0; t < 2; ++t)
#pragma unroll
                for (int r = 0; r < 16; ++r) {
                    float e = exp2f(st[t][r] - mnew);
                    st[t][r] = e;
                    rs += e;
                }
            rs += __shfl_xor(rs, 32, 64);
            l = l * alpha + rs;
            m2 = mnew;
#pragma unroll
            for (int t = 0; t < 4; ++t)
#pragma unroll
                for (int r = 0; r < 16; ++r) acc[t][r] *= alpha;
            unsigned cw[16];
#pragma unroll
            for (int i = 0; i < 16; ++i)
                cw[i] = pack2_bf16(st[i >> 3][2 * (i & 7)], st[i >> 3][2 * (i & 7) + 1]);
            bf16x8 pa[4];
#pragma unroll
            for (int ks = 0; ks < 4; ++ks) {
                const int base = (ks >> 1) * 8 + (ks & 1) * 4;
                union { unsigned u[4]; bf16x8 v; } pk;
#pragma unroll
                for (int e = 0; e < 2; ++e) {
                    unsigned A = cw[base + e];
                    unsigned B = cw[base + 2 + e];
                    unsigned tA = (unsigned)__shfl_xor((int)A, 32, 64);
                    unsigned tB = (unsigned)__shfl_xor((int)B, 32, 64);
                    pk.u[e] = hi ? tB : A;
                    pk.u[e + 2] = hi ? B : tA;
                }
                pa[ks] = pk.v;
            }
            const bf16* Vb = &Vt[buf][0];
            __builtin_amdgcn_s_setprio(1);
#pragma unroll
            for (int dt = 0; dt < 4; ++dt) {
                const int d = dt * 32 + ln;
#pragma unroll
                for (int ks = 0; ks < 4; ++ks) {
                    bf16x8 vf =
                        *(const bf16x8*)&Vb[d * 64 + (((2 * ks + hi) ^ (d & 7)) * 8)];
                    acc[dt] = mfma32(vf, pa[ks], acc[dt]);
                }
            }
            __builtin_amdgcn_s_setprio(0);
        }
        __syncthreads();
        buf ^= 1;
    }

    const float invl = 1.f / l;
    bf16* outp = qkv + (size_t)qrow * QKV_N + hq * DH;
#pragma unroll
    for (int dt = 0; dt < 4; ++dt)
#pragma unroll
        for (int rq = 0; rq < 4; ++rq) {
            bf16x4 o;
#pragma unroll
            for (int i = 0; i < 4; ++i) o[i] = (bf16)(acc[dt][rq * 4 + i] * invl);
            *(bf16x4*)(outp + dt * 32 + rq * 8 + hi * 4) = o;
        }
}

extern "C" void kernel_launch(void* const* d_in, const int* in_sizes, int n_in,
                              void* d_out, int out_size, void* d_ws, size_t ws_size,
                              hipStream_t stream) {
    const int* positions = (const int*)d_in[0];
    const float* hidden = (const float*)d_in[1];
    const float* w_qkv = (const float*)d_in[2];
    const float* w_o = (const float*)d_in[3];
    float* out = (float*)d_out;

    const size_t n_qkv = (size_t)S_LEN * QKV_N;
    const size_t n_vt = (size_t)NKV * DH * S_LEN;
    const size_t n_hid = (size_t)S_LEN * HID;
    const size_t n_wqkv = (size_t)QKV_N * HID;
    const size_t n_wo = (size_t)HID * HID;

    const size_t need_min = (n_qkv + n_vt) * sizeof(bf16);
    const size_t need_full = (n_qkv + n_vt + n_hid + n_wqkv + n_wo) * sizeof(bf16);
    if (ws_size < need_min) return;

    bf16* qkv = (bf16*)d_ws;
    bf16* vt_g = qkv + n_qkv;
    bf16* hid_b = vt_g + n_vt;
    bf16* wqkv_b = hid_b + n_hid;
    bf16* wo_b = wqkv_b + n_wqkv;
    const bool full = ws_size >= need_full;

    if (full) {
        const int c0 = (int)(n_hid / 8), c1 = (int)(n_wqkv / 8), c2 = (int)(n_wo / 8);
        cvt3_kernel<<<(c0 + c1 + c2 + 255) / 256, 256, 0, stream>>>(hidden, hid_b, c0,
                                                                    w_qkv, wqkv_b, c1,
                                                                    w_o, wo_b, c2);
        hipFuncSetAttribute(reinterpret_cast<const void*>(&gemm_8ph<256, bf16>),
                            hipFuncAttributeMaxDynamicSharedMemorySize, 131072);
        gemm_8ph<256, bf16><<<dim3(QKV_N / 256, S_LEN / 256), 512, 131072, stream>>>(
            hid_b, wqkv_b, qkv, HID, HID, QKV_N);
    } else {
        gemm_bt<<<dim3(QKV_N / 128, S_LEN / 128), 256, 0, stream>>>(hidden, w_qkv, qkv, HID, HID, QKV_N);
    }
    const int total = S_LEN * (NH + NKV) * 64;
    rope_kernel<<<(total + 255) / 256, 256, 0, stream>>>(qkv, positions);
    vtrans_kernel<<<dim3(S_LEN / 64, NKV), 256, 0, stream>>>(qkv, vt_g);
    attn_kernel<<<dim3(NH, S_LEN / 128), 256, 0, stream>>>(qkv, vt_g);
    if (full) {
        hipFuncSetAttribute(reinterpret_cast<const void*>(&gemm_8ph<128, float>),
                            hipFuncAttributeMaxDynamicSharedMemorySize, 98304);
        gemm_8ph<128, float><<<dim3(HID / 128, S_LEN / 256), 512, 98304, stream>>>(
            qkv, wo_b, out, HID, QKV_N, HID);
    } else {
        gemm_bt<<<dim3(HID / 128, S_LEN / 128), 256, 0, stream>>>(qkv, w_o, out, HID, QKV_N, HID);
    }
}